// Round 15
// baseline (105.477 us; speedup 1.0000x reference)
//
#include <hip/hip_runtime.h>

typedef unsigned short u16;
typedef __attribute__((ext_vector_type(8))) short short8;
typedef __attribute__((ext_vector_type(4))) float f32x4;
typedef __attribute__((ext_vector_type(16))) float f32x16;
typedef __attribute__((ext_vector_type(4))) unsigned short u16x4;
typedef __attribute__((ext_vector_type(4))) int i32x4;

__device__ __forceinline__ u16 f2b(float f) {
  unsigned u = __float_as_uint(f);
  unsigned r = (u + 0x7fffu + ((u >> 16) & 1u)) >> 16;
  return (u16)r;
}

__device__ __forceinline__ short8 pack8(f32x4 lo, f32x4 hi) {
  short8 r;
  r[0] = (short)f2b(lo[0]); r[1] = (short)f2b(lo[1]);
  r[2] = (short)f2b(lo[2]); r[3] = (short)f2b(lo[3]);
  r[4] = (short)f2b(hi[0]); r[5] = (short)f2b(hi[1]);
  r[6] = (short)f2b(hi[2]); r[7] = (short)f2b(hi[3]);
  return r;
}

__device__ __forceinline__ void gload16(const u16* g, u16* l) {
  __builtin_amdgcn_global_load_lds((const __attribute__((address_space(1))) void*)g,
                                   (__attribute__((address_space(3))) void*)l, 16, 0, 0);
}

// ---------------- prep: 4 weight transposes only (x-conversion fused into gemm_proj) ----------------
__global__ void prep_w(const float* __restrict__ Wq, const float* __restrict__ Wk,
                       const float* __restrict__ Wv, const float* __restrict__ Wo,
                       u16* __restrict__ wqT, u16* __restrict__ wkT,
                       u16* __restrict__ wvT, u16* __restrict__ woT) {
  __shared__ float t[32][33];
  int bid = blockIdx.x;
  const float* in; u16* out; int C, bx, by;
  if (bid < 1024)      { in = Wq; out = wqT; C = 1024; bx = bid & 31; by = bid >> 5; }
  else if (bid < 1088) { in = Wk; out = wkT; C = 64;   bid -= 1024; bx = bid & 1; by = bid >> 1; }
  else if (bid < 1152) { in = Wv; out = wvT; C = 64;   bid -= 1088; bx = bid & 1; by = bid >> 1; }
  else                 { in = Wo; out = woT; C = 1024; bid -= 1152; bx = bid & 31; by = bid >> 5; }
  const int R = 1024;
  const int c0 = bx * 32, r0 = by * 32;
  const int tx = threadIdx.x & 31, ty = threadIdx.x >> 5;
#pragma unroll
  for (int i = 0; i < 32; i += 8)
    t[ty + i][tx] = in[(size_t)(r0 + ty + i) * C + c0 + tx];
  __syncthreads();
#pragma unroll
  for (int i = 0; i < 32; i += 8)
    out[(size_t)(c0 + ty + i) * R + r0 + tx] = f2b(t[tx][ty + i]);
}

// ============ 64x128 tile, BK=64, 4-wave, single-buffer GEMM body (R10 proven) ============
#define GEMM_CORE(A_PTR, B_PTR)                                                        \
  __shared__ u16 As[4096];  /* 64 x 64 */                                              \
  __shared__ u16 Bs[8192];  /* 128 x 64 */                                             \
  const int tid = threadIdx.x;                                                         \
  const int lane = tid & 63, wid = tid >> 6;   /* 4 waves */                           \
  const int lg = lane >> 4, li = lane & 15;                                            \
  const int wr = wid >> 1, wc = wid & 1;                                               \
  f32x4 acc[2][4] = {};                                                                \
  const int lrow = lane >> 3, lslot = lane & 7;                                        \
  const int scol = 8 * (lslot ^ lrow);         /* pre-swizzled source col */           \
  const u16* Ab = (A_PTR) + (size_t)(m0 + wid * 16 + lrow) * 1024 + scol;              \
  const u16* Bb = (B_PTR) + (size_t)(wid * 32 + lrow) * 1024 + scol;                   \
  u16* const dA = As + wid * 1024;                                                     \
  u16* const dB = Bs + wid * 2048;                                                     \
  for (int t = 0; t < 16; ++t) {                                                       \
    const int k0 = t * 64;                                                             \
    __syncthreads();                                                                   \
    gload16(Ab + k0,        dA);                                                       \
    gload16(Ab + k0 + 8192, dA + 512);                                                 \
    _Pragma("unroll")                                                                  \
    for (int c_ = 0; c_ < 4; ++c_) gload16(Bb + k0 + c_ * 8192, dB + c_ * 512);        \
    __syncthreads();                                                                   \
    _Pragma("unroll")                                                                  \
    for (int kki = 0; kki < 2; ++kki) {                                                \
      short8 af[2], bfr[4];                                                            \
      _Pragma("unroll")                                                                \
      for (int mi = 0; mi < 2; ++mi) {                                                 \
        const int r = wr * 32 + mi * 16 + li;                                          \
        af[mi] = *(const short8*)&As[r * 64 + 8 * ((4 * kki + lg) ^ (r & 7))];         \
      }                                                                                \
      _Pragma("unroll")                                                                \
      for (int ni = 0; ni < 4; ++ni) {                                                 \
        const int r = wc * 64 + ni * 16 + li;                                          \
        bfr[ni] = *(const short8*)&Bs[r * 64 + 8 * ((4 * kki + lg) ^ (r & 7))];        \
      }                                                                                \
      _Pragma("unroll")                                                                \
      for (int mi = 0; mi < 2; ++mi)                                                   \
        _Pragma("unroll")                                                              \
        for (int ni = 0; ni < 4; ++ni)                                                 \
          acc[mi][ni] =                                                                \
              __builtin_amdgcn_mfma_f32_16x16x32_bf16(af[mi], bfr[ni], acc[mi][ni],    \
                                                      0, 0, 0);                        \
    }                                                                                  \
  }

// ---------------- fused projection GEMM: A = x (f32, converted in-staging) ----------------
// Q (by<8) + KV (by==8). A reg-staged: 2x f32x4 loads -> f2b pack -> ds_write_b128 to
// the same swizzled LDS address gload16 used (bitwise-identical values to the xb path).
__global__ __launch_bounds__(256) void gemm_proj(
    const float* __restrict__ X, const u16* __restrict__ BtQ, const u16* __restrict__ BtKV,
    u16* __restrict__ Qp, u16* __restrict__ K3, u16* __restrict__ Vt3, float scaleQ) {
  __shared__ u16 As[4096];  // 64 x 64
  __shared__ u16 Bs[8192];  // 128 x 64
  const int tid = threadIdx.x;
  const int lane = tid & 63, wid = tid >> 6;
  const int lg = lane >> 4, li = lane & 15;
  const int wr = wid >> 1, wc = wid & 1;
  const int m0 = blockIdx.x * 64;
  const int by = blockIdx.y;
  const bool isQ = (by < 8);
  const int n0 = isQ ? by * 128 : 0;

  f32x4 acc[2][4] = {};
  const int lrow = lane >> 3, lslot = lane & 7;
  const int scol = 8 * (lslot ^ lrow);
  const float* Axf = X + (size_t)(m0 + wid * 16 + lrow) * 1024 + scol;  // f32 source
  const u16* Bb = (isQ ? BtQ + (size_t)n0 * 1024 : BtKV) +
                  (size_t)(wid * 32 + lrow) * 1024 + scol;
  u16* const dA = As + wid * 1024;
  u16* const dB = Bs + wid * 2048;

  for (int t = 0; t < 16; ++t) {
    const int k0 = t * 64;
    __syncthreads();                         // WAR: prev compute done
    // A: global f32 -> regs -> bf16 -> swizzled LDS (reg-staging may scatter)
    const f32x4 a00 = *(const f32x4*)(Axf + k0);
    const f32x4 a01 = *(const f32x4*)(Axf + k0 + 4);
    const f32x4 a10 = *(const f32x4*)(Axf + k0 + 8192);
    const f32x4 a11 = *(const f32x4*)(Axf + k0 + 8196);
    // B: async gload (issues while A loads are in flight)
#pragma unroll
    for (int c_ = 0; c_ < 4; ++c_) gload16(Bb + k0 + c_ * 8192, dB + c_ * 512);
    *(short8*)(dA + lane * 8) = pack8(a00, a01);
    *(short8*)(dA + 512 + lane * 8) = pack8(a10, a11);
    __syncthreads();                         // drains vm+lgkm: staged data visible
#pragma unroll
    for (int kki = 0; kki < 2; ++kki) {
      short8 af[2], bfr[4];
#pragma unroll
      for (int mi = 0; mi < 2; ++mi) {
        const int r = wr * 32 + mi * 16 + li;
        af[mi] = *(const short8*)&As[r * 64 + 8 * ((4 * kki + lg) ^ (r & 7))];
      }
#pragma unroll
      for (int ni = 0; ni < 4; ++ni) {
        const int r = wc * 64 + ni * 16 + li;
        bfr[ni] = *(const short8*)&Bs[r * 64 + 8 * ((4 * kki + lg) ^ (r & 7))];
      }
#pragma unroll
      for (int mi = 0; mi < 2; ++mi)
#pragma unroll
        for (int ni = 0; ni < 4; ++ni)
          acc[mi][ni] =
              __builtin_amdgcn_mfma_f32_16x16x32_bf16(af[mi], bfr[ni], acc[mi][ni], 0, 0, 0);
    }
  }

#pragma unroll
  for (int mi = 0; mi < 2; ++mi) {
#pragma unroll
    for (int ni = 0; ni < 4; ++ni) {
      const int n = n0 + wc * 64 + ni * 16 + li;
#pragma unroll
      for (int i = 0; i < 4; ++i) {
        const int m = m0 + wr * 32 + mi * 16 + lg * 4 + i;
        const float v = acc[mi][ni][i];
        const int bb = m >> 10, ss = m & 1023;
        const int qt = ss >> 5, sl = ss & 31;
        if (isQ) {
          const int h = n >> 6, dd = n & 63;
          const int t = dd >> 4, h2 = (dd >> 3) & 1, j = dd & 7;
          Qp[(((((size_t)bb * 16 + h) * 32 + qt) * 4 + t) * 2 + h2) * 256 + sl * 8 + j] =
              f2b(v * scaleQ);
        } else if (n < 64) {
          const int t = n >> 4, h2 = (n >> 3) & 1, j = n & 7;
          K3[(((((size_t)bb * 32 + qt) * 4 + t) * 2 + h2) * 32 + sl) * 8 + j] = f2b(v);
        } else {
          const int d = n - 64;
          const int ks = sl >> 4, rem = sl & 15;
          const int h2 = (rem >> 2) & 1, j = (rem & 3) | ((rem >> 3) << 2);
          Vt3[(((((size_t)bb * 32 + qt) * 2 + ks) * 2 + h2) * 64 + d) * 8 + j] = f2b(v);
        }
      }
    }
  }
}

// ---------------- out-projection GEMM: f32 out + bias (single-buffer, R10 form) ----------------
__global__ __launch_bounds__(256) void gemm_out(
    const u16* __restrict__ A, const u16* __restrict__ Bt,
    float* __restrict__ Cf, const float* __restrict__ bias) {
  const int m0 = blockIdx.x * 64;
  const int n0 = blockIdx.y * 128;
  GEMM_CORE(A, Bt + (size_t)n0 * 1024)

#pragma unroll
  for (int mi = 0; mi < 2; ++mi)
#pragma unroll
    for (int ni = 0; ni < 4; ++ni) {
      const int n = n0 + wc * 64 + ni * 16 + li;
#pragma unroll
      for (int i = 0; i < 4; ++i) {
        const int m = m0 + wr * 32 + mi * 16 + lg * 4 + i;
        Cf[(size_t)m * 1024 + n] = acc[mi][ni][i] + bias[n];
      }
    }
}

// ---------------- causal MQA attention: both kv-splits in ONE block, in-block combine (R13) ----------------
__global__ __launch_bounds__(256, 4) void attn_mqa8(
    const u16* __restrict__ qp, const u16* __restrict__ k3,
    const u16* __restrict__ vt3, u16* __restrict__ ctxb) {
  __shared__ __align__(16) u16 smem[16384];   // 32 KB: K/V staging, then f32 exchange
  const int lane = threadIdx.x & 63, wid = threadIdx.x >> 6;
  const int bx = blockIdx.x;
  const int qt = 31 - (bx >> 6);              // longest first
  const int r6 = bx & 63;
  const int b  = r6 >> 3;
  const int hp = r6 & 7;
  const int hh = wid & 1;                     // head within pair
  const int s  = wid >> 1;                    // kv split
  const int h  = hp * 2 + hh;
  const int l31 = lane & 31, hi = lane >> 5;
  const int n0t = (qt + 2) >> 1;              // ceil((qt+1)/2)
  const int cs  = s ? (qt + 1 - n0t) : n0t;   // my split's iter count
  const int base = s ? n0t : 0;
  const int task = (b * 16 + h) * 32 + qt;

  const u16* k3b = k3 + (size_t)b * 65536;
  const u16* v3b = vt3 + (size_t)b * 65536;
  const int sreg = s * 4096;                  // split staging region (2 bufs x 2048)
  const int doff = hh * 1024;                 // this wave's half of the tile
  const int loff = lane * 8;

  const u16* qbase = qp + (size_t)task * 2048 + hi * 256 + l31 * 8;
  short8 qa[4];
#pragma unroll
  for (int t = 0; t < 4; ++t) qa[t] = *(const short8*)(qbase + t * 512);

  f32x16 acc0 = {}, acc1 = {};
  float lsum = 0.f;

  if (cs > 0) {
    const size_t o = (size_t)base * 2048 + doff + loff;
    gload16(k3b + o,       &smem[sreg + doff]);
    gload16(k3b + o + 512, &smem[sreg + doff + 512]);
    gload16(v3b + o,       &smem[8192 + sreg + doff]);
    gload16(v3b + o + 512, &smem[8192 + sreg + doff + 512]);
  }
  __syncthreads();

  int par = 0;
  for (int i = 0; i < n0t; ++i, par ^= 1) {
    if (i + 1 < cs) {
      const size_t o = (size_t)(base + i + 1) * 2048 + doff + loff;
      const int dst = sreg + (par ^ 1) * 2048 + doff;
      gload16(k3b + o,       &smem[dst]);
      gload16(k3b + o + 512, &smem[dst + 512]);
      gload16(v3b + o,       &smem[8192 + dst]);
      gload16(v3b + o + 512, &smem[8192 + dst + 512]);
    }
    if (i < cs) {
      const int kvt = base + i;
      const u16* lkb = &smem[sreg + par * 2048];
      const u16* lvb = &smem[8192 + sreg + par * 2048];
      short8 kc[4];
#pragma unroll
      for (int t = 0; t < 4; ++t)
        kc[t] = *(const short8*)&lkb[l31 * 8 + (t * 2 + hi) * 256];
      const u16* vtt = &lvb[hi * 512 + l31 * 8];
      const short8 vf0 = *(const short8*)(vtt);
      const short8 vf1 = *(const short8*)(vtt + 1024);
      const short8 vf2 = *(const short8*)(vtt + 256);
      const short8 vf3 = *(const short8*)(vtt + 1280);

      f32x16 st = {};
#pragma unroll
      for (int t = 0; t < 4; ++t)
        st = __builtin_amdgcn_mfma_f32_32x32x16_bf16(kc[t], qa[t], st, 0, 0, 0);

      if (kvt == qt) {
#pragma unroll
        for (int r = 0; r < 16; ++r) {
          const int crow = (r & 3) + 8 * (r >> 2) + 4 * hi;
          if (crow > l31) st[r] = -1e38f;
        }
      }
      float e[16];
#pragma unroll
      for (int r = 0; r < 16; ++r)
        asm("v_exp_f32 %0, %1" : "=v"(e[r]) : "v"(st[r]));
      lsum += ((e[0] + e[1]) + (e[2] + e[3])) + ((e[4] + e[5]) + (e[6] + e[7])) +
              (((e[8] + e[9]) + (e[10] + e[11])) + ((e[12] + e[13]) + (e[14] + e[15])));

      unsigned pw0, pw1, pw2, pw3, pw4, pw5, pw6, pw7;
      asm("v_cvt_pk_bf16_f32 %0, %1, %2" : "=v"(pw0) : "v"(e[0]),  "v"(e[1]));
      asm("v_cvt_pk_bf16_f32 %0, %1, %2" : "=v"(pw1) : "v"(e[2]),  "v"(e[3]));
      asm("v_cvt_pk_bf16_f32 %0, %1, %2" : "=v"(pw2) : "v"(e[4]),  "v"(e[5]));
      asm("v_cvt_pk_bf16_f32 %0, %1, %2" : "=v"(pw3) : "v"(e[6]),  "v"(e[7]));
      asm("v_cvt_pk_bf16_f32 %0, %1, %2" : "=v"(pw4) : "v"(e[8]),  "v"(e[9]));
      asm("v_cvt_pk_bf16_f32 %0, %1, %2" : "=v"(pw5) : "v"(e[10]), "v"(e[11]));
      asm("v_cvt_pk_bf16_f32 %0, %1, %2" : "=v"(pw6) : "v"(e[12]), "v"(e[13]));
      asm("v_cvt_pk_bf16_f32 %0, %1, %2" : "=v"(pw7) : "v"(e[14]), "v"(e[15]));
      i32x4 w0 = {(int)pw0, (int)pw1, (int)pw2, (int)pw3};
      i32x4 w1 = {(int)pw4, (int)pw5, (int)pw6, (int)pw7};
      const short8 pa0 = *(const short8*)&w0;
      const short8 pa1 = *(const short8*)&w1;

      acc0 = __builtin_amdgcn_mfma_f32_32x32x16_bf16(pa0, vf0, acc0, 0, 0, 0);
      acc0 = __builtin_amdgcn_mfma_f32_32x32x16_bf16(pa1, vf1, acc0, 0, 0, 0);
      acc1 = __builtin_amdgcn_mfma_f32_32x32x16_bf16(pa0, vf2, acc1, 0, 0, 0);
      acc1 = __builtin_amdgcn_mfma_f32_32x32x16_bf16(pa1, vf3, acc1, 0, 0, 0);
    }
    __syncthreads();
  }

  // ---- in-block combine of the two splits (fixed shared max -> add O and l) ----
  const float lfull = lsum + __shfl_xor(lsum, 32, 64);
  float* exf = (float*)smem;
  if (s == 1) {
    float* ab = exf + hh * 2048 + lane * 32;  // XOR-swizzled: bank-conflict-free
#pragma unroll
    for (int r = 0; r < 16; ++r) {
      ab[(2 * r) ^ (lane & 31)] = acc0[r];
      ab[(2 * r + 1) ^ (lane & 31)] = acc1[r];
    }
    exf[4096 + hh * 64 + lane] = lfull;
  }
  __syncthreads();
  if (s == 0) {
    const float lfp = exf[4096 + hh * 64 + lane];
    const float linv = 1.0f / (lfull + lfp);
    const float* ab = exf + hh * 2048 + lane * 32;
#pragma unroll
    for (int r = 0; r < 16; ++r) {
      const int crow = (r & 3) + 8 * (r >> 2) + 4 * hi;
      const float lr = __shfl(linv, crow, 64);
      const float o0 = acc0[r] + ab[(2 * r) ^ (lane & 31)];
      const float o1 = acc1[r] + ab[(2 * r + 1) ^ (lane & 31)];
      const size_t mrow = (size_t)(b * 1024 + qt * 32 + crow) * 1024 + h * 64;
      ctxb[mrow + l31] = f2b(o0 * lr);
      ctxb[mrow + 32 + l31] = f2b(o1 * lr);
    }
  }
}

// ---------------- host launch ----------------
extern "C" void kernel_launch(void* const* d_in, const int* in_sizes, int n_in,
                              void* d_out, int out_size, void* d_ws, size_t ws_size,
                              hipStream_t stream) {
  const float* x  = (const float*)d_in[0];
  const float* Wq = (const float*)d_in[1];
  const float* Wk = (const float*)d_in[2];
  const float* Wv = (const float*)d_in[3];
  const float* Wo = (const float*)d_in[4];
  const float* bo = (const float*)d_in[5];
  float* out = (float*)d_out;

  // workspace layout (u16 elements), lifetime overlays
  u16* ws16 = (u16*)d_ws;
  const size_t M1 = 1u << 20;
  u16* woT  = ws16;                  // [0,1M)
  u16* qp   = ws16 + 1 * M1;         // [1M,9M)   packed Q (live through attn)
  u16* k3   = ws16 + 9 * M1;         // [9M,9.5M)
  u16* vt3  = ws16 + 9 * M1 + (M1 >> 1);  // [9.5M,10M)
  u16* ctx  = ws16 + 10 * M1;        // [10M,18M) attn writes, gemm_out reads
  u16* wqT  = ws16 + 18 * M1;        // [18M,19M)
  u16* wkT  = ws16 + 19 * M1;        // [19M,19.0625M) (wvT contiguous after)
  u16* wvT  = wkT + 65536;

  prep_w<<<2176, 256, 0, stream>>>(Wq, Wk, Wv, Wo, wqT, wkT, wvT, woT);

  const float SCL = 0.125f * 1.44269504088896340736f;  // 1/sqrt(Dh) * log2(e) into Q
  gemm_proj<<<dim3(128, 9), 256, 0, stream>>>(x, wqT, wkT, qp, k3, vt3, SCL);

  attn_mqa8<<<2048, 256, 0, stream>>>(qp, k3, vt3, ctx);

  gemm_out<<<dim3(128, 8), 256, 0, stream>>>(ctx, woT, out, bo);
}

// Round 17
// 99.981 us; speedup vs baseline: 1.0550x; 1.0550x over previous
//
#include <hip/hip_runtime.h>

typedef unsigned short u16;
typedef __attribute__((ext_vector_type(8))) short short8;
typedef __attribute__((ext_vector_type(4))) float f32x4;
typedef __attribute__((ext_vector_type(16))) float f32x16;
typedef __attribute__((ext_vector_type(4))) unsigned short u16x4;
typedef __attribute__((ext_vector_type(8))) unsigned short u16x8;
typedef __attribute__((ext_vector_type(4))) int i32x4;

__device__ __forceinline__ u16 f2b(float f) {
  unsigned u = __float_as_uint(f);
  unsigned r = (u + 0x7fffu + ((u >> 16) & 1u)) >> 16;
  return (u16)r;
}

__device__ __forceinline__ void gload16(const u16* g, u16* l) {
  __builtin_amdgcn_global_load_lds((const __attribute__((address_space(1))) void*)g,
                                   (__attribute__((address_space(3))) void*)l, 16, 0, 0);
}

// ---------------- fused prep: x->bf16 (blocks 0..4095, 8 floats/thread) + 4 weight transposes ----------------
// Grid MUST be 4096 + 2176 = 6272 (Wq 1024 + Wk 64 + Wv 64 + Wo 1024).  [R16 bug: was 5248]
__global__ void prep(const float* __restrict__ x, const float* __restrict__ Wq,
                     const float* __restrict__ Wk, const float* __restrict__ Wv,
                     const float* __restrict__ Wo, u16* __restrict__ xb,
                     u16* __restrict__ wqT, u16* __restrict__ wkT,
                     u16* __restrict__ wvT, u16* __restrict__ woT) {
  __shared__ float t[32][33];
  int bid = blockIdx.x;
  if (bid < 4096) {
    const int i = (bid * 256 + threadIdx.x) * 8;
    const f32x4 a = *(const f32x4*)(x + i);
    const f32x4 b = *(const f32x4*)(x + i + 4);
    u16x8 o;
    o[0] = f2b(a[0]); o[1] = f2b(a[1]); o[2] = f2b(a[2]); o[3] = f2b(a[3]);
    o[4] = f2b(b[0]); o[5] = f2b(b[1]); o[6] = f2b(b[2]); o[7] = f2b(b[3]);
    *(u16x8*)(xb + i) = o;
    return;
  }
  bid -= 4096;
  const float* in; u16* out; int C, bx, by;
  if (bid < 1024)      { in = Wq; out = wqT; C = 1024; bx = bid & 31; by = bid >> 5; }
  else if (bid < 1088) { in = Wk; out = wkT; C = 64;   bid -= 1024; bx = bid & 1; by = bid >> 1; }
  else if (bid < 1152) { in = Wv; out = wvT; C = 64;   bid -= 1088; bx = bid & 1; by = bid >> 1; }
  else                 { in = Wo; out = woT; C = 1024; bid -= 1152; bx = bid & 31; by = bid >> 5; }
  const int R = 1024;
  const int c0 = bx * 32, r0 = by * 32;
  const int tx = threadIdx.x & 31, ty = threadIdx.x >> 5;
#pragma unroll
  for (int i = 0; i < 32; i += 8)
    t[ty + i][tx] = in[(size_t)(r0 + ty + i) * C + c0 + tx];
  __syncthreads();
#pragma unroll
  for (int i = 0; i < 32; i += 8)
    out[(size_t)(c0 + ty + i) * R + r0 + tx] = f2b(t[tx][ty + i]);
}

// ============ 64x128 tile, BK=64, 4-wave, single-buffer GEMM body (R10 proven) ============
#define GEMM_CORE(A_PTR, B_PTR)                                                        \
  __shared__ u16 As[4096];  /* 64 x 64 */                                              \
  __shared__ u16 Bs[8192];  /* 128 x 64 */                                             \
  const int tid = threadIdx.x;                                                         \
  const int lane = tid & 63, wid = tid >> 6;   /* 4 waves */                           \
  const int lg = lane >> 4, li = lane & 15;                                            \
  const int wr = wid >> 1, wc = wid & 1;                                               \
  f32x4 acc[2][4] = {};                                                                \
  const int lrow = lane >> 3, lslot = lane & 7;                                        \
  const int scol = 8 * (lslot ^ lrow);         /* pre-swizzled source col */           \
  const u16* Ab = (A_PTR) + (size_t)(m0 + wid * 16 + lrow) * 1024 + scol;              \
  const u16* Bb = (B_PTR) + (size_t)(wid * 32 + lrow) * 1024 + scol;                   \
  u16* const dA = As + wid * 1024;                                                     \
  u16* const dB = Bs + wid * 2048;                                                     \
  for (int t = 0; t < 16; ++t) {                                                       \
    const int k0 = t * 64;                                                             \
    __syncthreads();                                                                   \
    gload16(Ab + k0,        dA);                                                       \
    gload16(Ab + k0 + 8192, dA + 512);                                                 \
    _Pragma("unroll")                                                                  \
    for (int c_ = 0; c_ < 4; ++c_) gload16(Bb + k0 + c_ * 8192, dB + c_ * 512);        \
    __syncthreads();                                                                   \
    _Pragma("unroll")                                                                  \
    for (int kki = 0; kki < 2; ++kki) {                                                \
      short8 af[2], bfr[4];                                                            \
      _Pragma("unroll")                                                                \
      for (int mi = 0; mi < 2; ++mi) {                                                 \
        const int r = wr * 32 + mi * 16 + li;                                          \
        af[mi] = *(const short8*)&As[r * 64 + 8 * ((4 * kki + lg) ^ (r & 7))];         \
      }                                                                                \
      _Pragma("unroll")                                                                \
      for (int ni = 0; ni < 4; ++ni) {                                                 \
        const int r = wc * 64 + ni * 16 + li;                                          \
        bfr[ni] = *(const short8*)&Bs[r * 64 + 8 * ((4 * kki + lg) ^ (r & 7))];        \
      }                                                                                \
      _Pragma("unroll")                                                                \
      for (int mi = 0; mi < 2; ++mi)                                                   \
        _Pragma("unroll")                                                              \
        for (int ni = 0; ni < 4; ++ni)                                                 \
          acc[mi][ni] =                                                                \
              __builtin_amdgcn_mfma_f32_16x16x32_bf16(af[mi], bfr[ni], acc[mi][ni],    \
                                                      0, 0, 0);                        \
    }                                                                                  \
  }

// ---------------- fused projection GEMM: Q (by<8) + KV (by==8) ----------------
__global__ __launch_bounds__(256) void gemm_proj(
    const u16* __restrict__ A, const u16* __restrict__ BtQ, const u16* __restrict__ BtKV,
    u16* __restrict__ Qp, u16* __restrict__ K3, u16* __restrict__ Vt3, float scaleQ) {
  const int m0 = blockIdx.x * 64;
  const int by = blockIdx.y;
  const bool isQ = (by < 8);
  const int n0 = isQ ? by * 128 : 0;
  GEMM_CORE(A, (isQ ? BtQ + (size_t)n0 * 1024 : BtKV))

#pragma unroll
  for (int mi = 0; mi < 2; ++mi) {
#pragma unroll
    for (int ni = 0; ni < 4; ++ni) {
      const int n = n0 + wc * 64 + ni * 16 + li;
#pragma unroll
      for (int i = 0; i < 4; ++i) {
        const int m = m0 + wr * 32 + mi * 16 + lg * 4 + i;
        const float v = acc[mi][ni][i];
        const int bb = m >> 10, ss = m & 1023;
        const int qt = ss >> 5, sl = ss & 31;
        if (isQ) {
          const int h = n >> 6, dd = n & 63;
          const int t = dd >> 4, h2 = (dd >> 3) & 1, j = dd & 7;
          Qp[(((((size_t)bb * 16 + h) * 32 + qt) * 4 + t) * 2 + h2) * 256 + sl * 8 + j] =
              f2b(v * scaleQ);
        } else if (n < 64) {
          const int t = n >> 4, h2 = (n >> 3) & 1, j = n & 7;
          K3[(((((size_t)bb * 32 + qt) * 4 + t) * 2 + h2) * 32 + sl) * 8 + j] = f2b(v);
        } else {
          const int d = n - 64;
          const int ks = sl >> 4, rem = sl & 15;
          const int h2 = (rem >> 2) & 1, j = (rem & 3) | ((rem >> 3) << 2);
          Vt3[(((((size_t)bb * 32 + qt) * 2 + ks) * 2 + h2) * 64 + d) * 8 + j] = f2b(v);
        }
      }
    }
  }
}

// ---------------- out-projection GEMM: f32 out + bias (single-buffer, R10 form) ----------------
__global__ __launch_bounds__(256) void gemm_out(
    const u16* __restrict__ A, const u16* __restrict__ Bt,
    float* __restrict__ Cf, const float* __restrict__ bias) {
  const int m0 = blockIdx.x * 64;
  const int n0 = blockIdx.y * 128;
  GEMM_CORE(A, Bt + (size_t)n0 * 1024)

#pragma unroll
  for (int mi = 0; mi < 2; ++mi)
#pragma unroll
    for (int ni = 0; ni < 4; ++ni) {
      const int n = n0 + wc * 64 + ni * 16 + li;
#pragma unroll
      for (int i = 0; i < 4; ++i) {
        const int m = m0 + wr * 32 + mi * 16 + lg * 4 + i;
        Cf[(size_t)m * 1024 + n] = acc[mi][ni][i] + bias[n];
      }
    }
}

// ---------------- causal MQA attention: both kv-splits in ONE block, in-block combine (R13) ----------------
__global__ __launch_bounds__(256, 4) void attn_mqa8(
    const u16* __restrict__ qp, const u16* __restrict__ k3,
    const u16* __restrict__ vt3, u16* __restrict__ ctxb) {
  __shared__ __align__(16) u16 smem[16384];   // 32 KB: K/V staging, then f32 exchange
  const int lane = threadIdx.x & 63, wid = threadIdx.x >> 6;
  const int bx = blockIdx.x;
  const int qt = 31 - (bx >> 6);              // longest first
  const int r6 = bx & 63;
  const int b  = r6 >> 3;
  const int hp = r6 & 7;
  const int hh = wid & 1;                     // head within pair
  const int s  = wid >> 1;                    // kv split
  const int h  = hp * 2 + hh;
  const int l31 = lane & 31, hi = lane >> 5;
  const int n0t = (qt + 2) >> 1;              // ceil((qt+1)/2)
  const int cs  = s ? (qt + 1 - n0t) : n0t;   // my split's iter count
  const int base = s ? n0t : 0;
  const int task = (b * 16 + h) * 32 + qt;

  const u16* k3b = k3 + (size_t)b * 65536;
  const u16* v3b = vt3 + (size_t)b * 65536;
  const int sreg = s * 4096;                  // split staging region (2 bufs x 2048)
  const int doff = hh * 1024;                 // this wave's half of the tile
  const int loff = lane * 8;

  const u16* qbase = qp + (size_t)task * 2048 + hi * 256 + l31 * 8;
  short8 qa[4];
#pragma unroll
  for (int t = 0; t < 4; ++t) qa[t] = *(const short8*)(qbase + t * 512);

  f32x16 acc0 = {}, acc1 = {};
  float lsum = 0.f;

  if (cs > 0) {
    const size_t o = (size_t)base * 2048 + doff + loff;
    gload16(k3b + o,       &smem[sreg + doff]);
    gload16(k3b + o + 512, &smem[sreg + doff + 512]);
    gload16(v3b + o,       &smem[8192 + sreg + doff]);
    gload16(v3b + o + 512, &smem[8192 + sreg + doff + 512]);
  }
  __syncthreads();

  int par = 0;
  for (int i = 0; i < n0t; ++i, par ^= 1) {
    if (i + 1 < cs) {
      const size_t o = (size_t)(base + i + 1) * 2048 + doff + loff;
      const int dst = sreg + (par ^ 1) * 2048 + doff;
      gload16(k3b + o,       &smem[dst]);
      gload16(k3b + o + 512, &smem[dst + 512]);
      gload16(v3b + o,       &smem[8192 + dst]);
      gload16(v3b + o + 512, &smem[8192 + dst + 512]);
    }
    if (i < cs) {
      const int kvt = base + i;
      const u16* lkb = &smem[sreg + par * 2048];
      const u16* lvb = &smem[8192 + sreg + par * 2048];
      short8 kc[4];
#pragma unroll
      for (int t = 0; t < 4; ++t)
        kc[t] = *(const short8*)&lkb[l31 * 8 + (t * 2 + hi) * 256];
      const u16* vtt = &lvb[hi * 512 + l31 * 8];
      const short8 vf0 = *(const short8*)(vtt);
      const short8 vf1 = *(const short8*)(vtt + 1024);
      const short8 vf2 = *(const short8*)(vtt + 256);
      const short8 vf3 = *(const short8*)(vtt + 1280);

      f32x16 st = {};
#pragma unroll
      for (int t = 0; t < 4; ++t)
        st = __builtin_amdgcn_mfma_f32_32x32x16_bf16(kc[t], qa[t], st, 0, 0, 0);

      if (kvt == qt) {
#pragma unroll
        for (int r = 0; r < 16; ++r) {
          const int crow = (r & 3) + 8 * (r >> 2) + 4 * hi;
          if (crow > l31) st[r] = -1e38f;
        }
      }
      float e[16];
#pragma unroll
      for (int r = 0; r < 16; ++r)
        asm("v_exp_f32 %0, %1" : "=v"(e[r]) : "v"(st[r]));
      lsum += ((e[0] + e[1]) + (e[2] + e[3])) + ((e[4] + e[5]) + (e[6] + e[7])) +
              (((e[8] + e[9]) + (e[10] + e[11])) + ((e[12] + e[13]) + (e[14] + e[15])));

      unsigned pw0, pw1, pw2, pw3, pw4, pw5, pw6, pw7;
      asm("v_cvt_pk_bf16_f32 %0, %1, %2" : "=v"(pw0) : "v"(e[0]),  "v"(e[1]));
      asm("v_cvt_pk_bf16_f32 %0, %1, %2" : "=v"(pw1) : "v"(e[2]),  "v"(e[3]));
      asm("v_cvt_pk_bf16_f32 %0, %1, %2" : "=v"(pw2) : "v"(e[4]),  "v"(e[5]));
      asm("v_cvt_pk_bf16_f32 %0, %1, %2" : "=v"(pw3) : "v"(e[6]),  "v"(e[7]));
      asm("v_cvt_pk_bf16_f32 %0, %1, %2" : "=v"(pw4) : "v"(e[8]),  "v"(e[9]));
      asm("v_cvt_pk_bf16_f32 %0, %1, %2" : "=v"(pw5) : "v"(e[10]), "v"(e[11]));
      asm("v_cvt_pk_bf16_f32 %0, %1, %2" : "=v"(pw6) : "v"(e[12]), "v"(e[13]));
      asm("v_cvt_pk_bf16_f32 %0, %1, %2" : "=v"(pw7) : "v"(e[14]), "v"(e[15]));
      i32x4 w0 = {(int)pw0, (int)pw1, (int)pw2, (int)pw3};
      i32x4 w1 = {(int)pw4, (int)pw5, (int)pw6, (int)pw7};
      const short8 pa0 = *(const short8*)&w0;
      const short8 pa1 = *(const short8*)&w1;

      acc0 = __builtin_amdgcn_mfma_f32_32x32x16_bf16(pa0, vf0, acc0, 0, 0, 0);
      acc0 = __builtin_amdgcn_mfma_f32_32x32x16_bf16(pa1, vf1, acc0, 0, 0, 0);
      acc1 = __builtin_amdgcn_mfma_f32_32x32x16_bf16(pa0, vf2, acc1, 0, 0, 0);
      acc1 = __builtin_amdgcn_mfma_f32_32x32x16_bf16(pa1, vf3, acc1, 0, 0, 0);
    }
    __syncthreads();
  }

  // ---- in-block combine of the two splits (fixed shared max -> add O and l) ----
  const float lfull = lsum + __shfl_xor(lsum, 32, 64);
  float* exf = (float*)smem;
  if (s == 1) {
    float* ab = exf + hh * 2048 + lane * 32;  // XOR-swizzled: bank-conflict-free
#pragma unroll
    for (int r = 0; r < 16; ++r) {
      ab[(2 * r) ^ (lane & 31)] = acc0[r];
      ab[(2 * r + 1) ^ (lane & 31)] = acc1[r];
    }
    exf[4096 + hh * 64 + lane] = lfull;
  }
  __syncthreads();
  if (s == 0) {
    const float lfp = exf[4096 + hh * 64 + lane];
    const float linv = 1.0f / (lfull + lfp);
    const float* ab = exf + hh * 2048 + lane * 32;
#pragma unroll
    for (int r = 0; r < 16; ++r) {
      const int crow = (r & 3) + 8 * (r >> 2) + 4 * hi;
      const float lr = __shfl(linv, crow, 64);
      const float o0 = acc0[r] + ab[(2 * r) ^ (lane & 31)];
      const float o1 = acc1[r] + ab[(2 * r + 1) ^ (lane & 31)];
      const size_t mrow = (size_t)(b * 1024 + qt * 32 + crow) * 1024 + h * 64;
      ctxb[mrow + l31] = f2b(o0 * lr);
      ctxb[mrow + 32 + l31] = f2b(o1 * lr);
    }
  }
}

// ---------------- host launch ----------------
extern "C" void kernel_launch(void* const* d_in, const int* in_sizes, int n_in,
                              void* d_out, int out_size, void* d_ws, size_t ws_size,
                              hipStream_t stream) {
  const float* x  = (const float*)d_in[0];
  const float* Wq = (const float*)d_in[1];
  const float* Wk = (const float*)d_in[2];
  const float* Wv = (const float*)d_in[3];
  const float* Wo = (const float*)d_in[4];
  const float* bo = (const float*)d_in[5];
  float* out = (float*)d_out;

  // workspace layout (u16 elements), lifetime overlays; total 20M u16 = 40 MB
  u16* ws16 = (u16*)d_ws;
  const size_t M1 = 1u << 20;
  u16* woT  = ws16;                  // [0,1M)
  u16* qp   = ws16 + 1 * M1;         // [1M,9M)   packed Q (live through attn)
  u16* k3   = ws16 + 9 * M1;         // [9M,9.5M)
  u16* vt3  = ws16 + 9 * M1 + (M1 >> 1);  // [9.5M,10M)
  u16* xb   = ws16 + 10 * M1;        // [10M,18M) x bf16 (dead after gemm_proj)
  u16* ctx  = ws16 + 10 * M1;        // overlays xb: attn writes, gemm_out reads
  u16* wqT  = ws16 + 18 * M1;        // [18M,19M)
  u16* wkT  = ws16 + 19 * M1;        // [19M,19.0625M) (wvT contiguous after)
  u16* wvT  = wkT + 65536;

  prep<<<6272, 256, 0, stream>>>(x, Wq, Wk, Wv, Wo, xb, wqT, wkT, wvT, woT);

  const float SCL = 0.125f * 1.44269504088896340736f;  // 1/sqrt(Dh) * log2(e) into Q
  gemm_proj<<<dim3(128, 9), 256, 0, stream>>>(xb, wqT, wkT, qp, k3, vt3, SCL);

  attn_mqa8<<<2048, 256, 0, stream>>>(qp, k3, vt3, ctx);

  gemm_out<<<dim3(128, 8), 256, 0, stream>>>(ctx, woT, out, bo);
}